// Round 7
// baseline (277.541 us; speedup 1.0000x reference)
//
#include <hip/hip_runtime.h>

// net_71322226917474: 2-layer GNN (SAGE-like) on MI355X.
// dst = repeat(arange(N),16) -> edges of node j are j*16..j*16+15, deg==16.
// bf16 matmul path (threshold 0.645), f32 accumulate.
// R7 = R2 structure + (a) launch_bounds(256,6): VGPR cap 85 for load clustering
//      and 12.2 blocks/CU / 6 resident = 2.03 rounds (tail-aligned occupancy);
//      (b) 16-lane groups own TWO dst rows with interleaved independent
//      accumulate chains -> >=2x outstanding loads floor.

#define N_NODES 100000
#define DEG 16
#define F 128
#define K2 256      // combined K = [agg | h]
#define TILE 32     // rows per block; 100000 = 3125 * 32 exactly
#define LDP 264     // padded LDS row (shorts): 528B stride

typedef __attribute__((ext_vector_type(8))) short short8;
typedef __attribute__((ext_vector_type(4))) float f32x4;
typedef __attribute__((ext_vector_type(4))) unsigned short us4;
typedef __attribute__((ext_vector_type(8))) unsigned short us8;

__device__ __forceinline__ unsigned short f2bf(float f) {
    unsigned u = __builtin_bit_cast(unsigned, f);
    u += 0x7FFFu + ((u >> 16) & 1u);   // RNE
    return (unsigned short)(u >> 16);
}
__device__ __forceinline__ float bf2f(unsigned short h) {
    return __builtin_bit_cast(float, (unsigned)h << 16);
}

// ---- prep: x (f32) -> xb (bf16) ----
__global__ void cast_x_kernel(const float* __restrict__ x, unsigned short* __restrict__ xb) {
    int i = blockIdx.x * blockDim.x + threadIdx.x;
    const float4 v = ((const float4*)x)[i];
    us4 o; o.x = f2bf(v.x); o.y = f2bf(v.y); o.z = f2bf(v.z); o.w = f2bf(v.w);
    ((us4*)xb)[i] = o;
}

// ---- prep: Bt[layer][n][k] = bf16( k<128 ? W[n][k] : Wr[n][k-128] ) ----
__global__ void build_bt_kernel(const float* __restrict__ W0, const float* __restrict__ Wr0,
                                const float* __restrict__ W1, const float* __restrict__ Wr1,
                                unsigned short* __restrict__ Bt) {
    int t = blockIdx.x * 256 + threadIdx.x;
    int layer = t >> 15;
    int n = (t >> 8) & 127;
    int k = t & 255;
    const float* W  = layer ? W1  : W0;
    const float* Wr = layer ? Wr1 : Wr0;
    float v = (k < 128) ? W[n * 128 + k] : Wr[n * 128 + (k - 128)];
    Bt[t] = f2bf(v);
}

// ---- one layer: gather agg, [agg|h] @ Bt^T via MFMA, relu, -agg/16 ----
__global__ __launch_bounds__(256, 6) void layer_kernel(
    const unsigned short* __restrict__ hb,   // [N][128] bf16 input
    const unsigned short* __restrict__ Bt,   // [128][256] bf16 combined weights
    const float* __restrict__ bias,          // [128] f32
    const int* __restrict__ src,             // [E] edge sources (dst implicit: e/16)
    unsigned short* __restrict__ outb,       // bf16 out (layer 0) or null
    float* __restrict__ outf)                // f32 out (layer 1) or null
{
    __shared__ unsigned short sIn[TILE][LDP];   // [row][0:128)=agg, [128:256)=h
    const int tid = threadIdx.x;
    const int r0 = blockIdx.x * TILE;

    // ---- gather: 16 groups of 16 lanes; each group owns rows 2g, 2g+1 with
    //      independent interleaved accumulate chains ----
    const int g16 = tid >> 4, l16 = tid & 15;
    const int wbase = tid & 48;                 // group's lane base within wave
    const int rA = g16 * 2, rB = rA + 1;
    const int gA = r0 + rA, gB = r0 + rB;

    const int suA = src[gA * DEG + l16];
    const int suB = src[gB * DEG + l16];

    // own-row h -> second K-half (independent, issued early)
    const us8 ownA = *(const us8*)(hb + (size_t)gA * F + l16 * 8);
    const us8 ownB = *(const us8*)(hb + (size_t)gB * F + l16 * 8);

    float A0 = 0.f, A1 = 0.f, A2 = 0.f, A3 = 0.f, A4 = 0.f, A5 = 0.f, A6 = 0.f, A7 = 0.f;
    float B0 = 0.f, B1 = 0.f, B2 = 0.f, B3 = 0.f, B4 = 0.f, B5 = 0.f, B6 = 0.f, B7 = 0.f;
    #pragma unroll
    for (int e = 0; e < DEG; ++e) {
        const int iA = __shfl(suA, wbase + e);
        const int iB = __shfl(suB, wbase + e);
        const us8 vA = *(const us8*)(hb + (size_t)iA * F + l16 * 8);
        const us8 vB = *(const us8*)(hb + (size_t)iB * F + l16 * 8);
        A0 += bf2f(vA[0]); A1 += bf2f(vA[1]); A2 += bf2f(vA[2]); A3 += bf2f(vA[3]);
        A4 += bf2f(vA[4]); A5 += bf2f(vA[5]); A6 += bf2f(vA[6]); A7 += bf2f(vA[7]);
        B0 += bf2f(vB[0]); B1 += bf2f(vB[1]); B2 += bf2f(vB[2]); B3 += bf2f(vB[3]);
        B4 += bf2f(vB[4]); B5 += bf2f(vB[5]); B6 += bf2f(vB[6]); B7 += bf2f(vB[7]);
    }
    {
        us8 oA, oB;
        oA[0] = f2bf(A0); oA[1] = f2bf(A1); oA[2] = f2bf(A2); oA[3] = f2bf(A3);
        oA[4] = f2bf(A4); oA[5] = f2bf(A5); oA[6] = f2bf(A6); oA[7] = f2bf(A7);
        oB[0] = f2bf(B0); oB[1] = f2bf(B1); oB[2] = f2bf(B2); oB[3] = f2bf(B3);
        oB[4] = f2bf(B4); oB[5] = f2bf(B5); oB[6] = f2bf(B6); oB[7] = f2bf(B7);
        *(us8*)&sIn[rA][l16 * 8] = oA;
        *(us8*)&sIn[rB][l16 * 8] = oB;
        *(us8*)&sIn[rA][128 + l16 * 8] = ownA;
        *(us8*)&sIn[rB][128 + l16 * 8] = ownB;
    }
    __syncthreads();

    // ---- MFMA stage: wave w -> row-tile (w>>1), col-fragments (w&1)*4 .. +3 ----
    const int w = tid >> 6, wl = tid & 63;
    const int lc = wl & 15;
    const int kb = (wl >> 4) * 8;
    const int rt = w >> 1;
    const int cfb = (w & 1) * 4;
    f32x4 acc[4];
    #pragma unroll
    for (int cf = 0; cf < 4; ++cf) acc[cf] = (f32x4){0.f, 0.f, 0.f, 0.f};

    #pragma unroll
    for (int ks = 0; ks < 8; ++ks) {
        short8 af = *(const short8*)&sIn[rt * 16 + lc][ks * 32 + kb];
        #pragma unroll
        for (int cf = 0; cf < 4; ++cf) {
            short8 bfr = *(const short8*)(Bt + (size_t)((cfb + cf) * 16 + lc) * K2 + ks * 32 + kb);
            acc[cf] = __builtin_amdgcn_mfma_f32_16x16x32_bf16(af, bfr, acc[cf], 0, 0, 0);
        }
    }

    // ---- epilogue: out = relu(acc + b) - agg/16 ----
    const int rbase = (wl >> 4) * 4;   // C/D: col=lane&15, row=(lane>>4)*4+reg
    #pragma unroll
    for (int cf = 0; cf < 4; ++cf) {
        const int col = (cfb + cf) * 16 + lc;
        const float bv = bias[col];
        #pragma unroll
        for (int j = 0; j < 4; ++j) {
            const int trow = rt * 16 + rbase + j;
            const int grow = r0 + trow;
            float v = fmaxf(acc[cf][j] + bv, 0.f) - bf2f(sIn[trow][col]) * (1.0f / DEG);
            if (outb) outb[(size_t)grow * F + col] = f2bf(v);
            else      outf[(size_t)grow * F + col] = v;
        }
    }
}

extern "C" void kernel_launch(void* const* d_in, const int* in_sizes, int n_in,
                              void* d_out, int out_size, void* d_ws, size_t ws_size,
                              hipStream_t stream) {
    const float* x   = (const float*)d_in[0];
    const int*   ei  = (const int*)d_in[1];    // [2,E] row-major: src first
    const float* W0  = (const float*)d_in[2];
    const float* b0  = (const float*)d_in[3];
    const float* Wr0 = (const float*)d_in[4];
    const float* W1  = (const float*)d_in[5];
    const float* b1  = (const float*)d_in[6];
    const float* Wr1 = (const float*)d_in[7];
    const int* src = ei;                        // first E entries

    // workspace layout: xb 25.6MB | h1b 25.6MB | Bt 128KB
    unsigned short* xb  = (unsigned short*)d_ws;
    unsigned short* h1b = xb  + (size_t)N_NODES * F;
    unsigned short* Bt  = h1b + (size_t)N_NODES * F;

    cast_x_kernel<<<(N_NODES * F / 4 + 255) / 256, 256, 0, stream>>>(x, xb);
    build_bt_kernel<<<256, 256, 0, stream>>>(W0, Wr0, W1, Wr1, Bt);

    const int nb = N_NODES / TILE;   // 3125
    layer_kernel<<<nb, 256, 0, stream>>>(xb,  Bt,         b0, src, h1b,    nullptr);
    layer_kernel<<<nb, 256, 0, stream>>>(h1b, Bt + 32768, b1, src, nullptr, (float*)d_out);
}

// Round 8
// 186.106 us; speedup vs baseline: 1.4913x; 1.4913x over previous
//
#include <hip/hip_runtime.h>

// net_71322226917474: 2-layer GNN (SAGE-like) on MI355X.
// dst = repeat(arange(N),16) -> edges of node j are j*16..j*16+15, deg==16.
// bf16 matmul path (threshold 0.645), f32 accumulate.
// R8 = R2 structure, but the gather uses inline-asm global_load_dwordx4 with
//      hand-counted s_waitcnt vmcnt(N): forces an 8-deep load window per lane
//      that the compiler can neither serialize nor spill (R3/R4/R7 post-mortems:
//      hipcc's allocator refuses compiler-visible load batching).

#define N_NODES 100000
#define DEG 16
#define F 128
#define K2 256      // combined K = [agg | h]
#define TILE 32     // rows per block; 100000 = 3125 * 32 exactly
#define LDP 264     // padded LDS row (shorts): 528B stride

typedef __attribute__((ext_vector_type(8))) short short8;
typedef __attribute__((ext_vector_type(4))) float f32x4;
typedef __attribute__((ext_vector_type(4))) unsigned short us4;
typedef __attribute__((ext_vector_type(8))) unsigned short us8;
typedef __attribute__((ext_vector_type(4))) unsigned int uint4v;

__device__ __forceinline__ unsigned short f2bf(float f) {
    unsigned u = __builtin_bit_cast(unsigned, f);
    u += 0x7FFFu + ((u >> 16) & 1u);   // RNE
    return (unsigned short)(u >> 16);
}
__device__ __forceinline__ float bf2f(unsigned short h) {
    return __builtin_bit_cast(float, (unsigned)h << 16);
}
__device__ __forceinline__ float bflo(unsigned u) {
    return __builtin_bit_cast(float, u << 16);
}
__device__ __forceinline__ float bfhi(unsigned u) {
    return __builtin_bit_cast(float, u & 0xffff0000u);
}

// forced async-ish load: compiler cannot reorder/serialize/spill the window
#define GLOAD4(dst, off) \
    asm volatile("global_load_dwordx4 %0, %1, %2" \
                 : "=v"(dst) : "v"(off), "s"(hb) : "memory")

#define VMWAIT(n) do { \
    asm volatile("s_waitcnt vmcnt(" #n ")" ::: "memory"); \
    __builtin_amdgcn_sched_barrier(0); } while (0)

#define CONSUME(q) do { \
    a0 += bflo((q)[0]); a1 += bfhi((q)[0]); \
    a2 += bflo((q)[1]); a3 += bfhi((q)[1]); \
    a4 += bflo((q)[2]); a5 += bfhi((q)[2]); \
    a6 += bflo((q)[3]); a7 += bfhi((q)[3]); } while (0)

// ---- prep: x (f32) -> xb (bf16) ----
__global__ void cast_x_kernel(const float* __restrict__ x, unsigned short* __restrict__ xb) {
    int i = blockIdx.x * blockDim.x + threadIdx.x;
    const float4 v = ((const float4*)x)[i];
    us4 o; o.x = f2bf(v.x); o.y = f2bf(v.y); o.z = f2bf(v.z); o.w = f2bf(v.w);
    ((us4*)xb)[i] = o;
}

// ---- prep: Bt[layer][n][k] = bf16( k<128 ? W[n][k] : Wr[n][k-128] ) ----
__global__ void build_bt_kernel(const float* __restrict__ W0, const float* __restrict__ Wr0,
                                const float* __restrict__ W1, const float* __restrict__ Wr1,
                                unsigned short* __restrict__ Bt) {
    int t = blockIdx.x * 256 + threadIdx.x;
    int layer = t >> 15;
    int n = (t >> 8) & 127;
    int k = t & 255;
    const float* W  = layer ? W1  : W0;
    const float* Wr = layer ? Wr1 : Wr0;
    float v = (k < 128) ? W[n * 128 + k] : Wr[n * 128 + (k - 128)];
    Bt[t] = f2bf(v);
}

// ---- one layer: gather agg, [agg|h] @ Bt^T via MFMA, relu, -agg/16 ----
__global__ __launch_bounds__(256, 6) void layer_kernel(
    const unsigned short* __restrict__ hb,   // [N][128] bf16 input
    const unsigned short* __restrict__ Bt,   // [128][256] bf16 combined weights
    const float* __restrict__ bias,          // [128] f32
    const int* __restrict__ src,             // [E] edge sources (dst implicit: e/16)
    unsigned short* __restrict__ outb,       // bf16 out (layer 0) or null
    float* __restrict__ outf)                // f32 out (layer 1) or null
{
    __shared__ unsigned short sIn[TILE][LDP];   // [row][0:128)=agg, [128:256)=h
    const int tid = threadIdx.x;
    const int r0 = blockIdx.x * TILE;

    const int g16 = tid >> 4, l16 = tid & 15;
    const int wbase = tid & 48;                 // group's lane base within wave
    const int rA = g16 * 2, rB = rA + 1;
    const int gA = r0 + rA, gB = r0 + rB;

    // src indices for both rows (consumed pre-region A / post-region A)
    const int suA = src[gA * DEG + l16];
    const int suB = src[gB * DEG + l16];

    // own-row h -> second K-half of sIn. Loaded AND stored before the asm
    // region: the compiler's own vmcnt wait (before these ds_writes) drains
    // all its VMEM, so the asm region's vmcnt counting is exact.
    *(us8*)&sIn[rA][128 + l16 * 8] = *(const us8*)(hb + (size_t)gA * F + l16 * 8);
    *(us8*)&sIn[rB][128 + l16 * 8] = *(const us8*)(hb + (size_t)gB * F + l16 * 8);

    // ================= row A gather (asm window) =================
    {
        unsigned o[16];
        #pragma unroll
        for (int e = 0; e < 16; ++e)
            o[e] = (unsigned)__shfl(suA, wbase + e) * 256u + (unsigned)l16 * 16u;
        float a0 = 0.f, a1 = 0.f, a2 = 0.f, a3 = 0.f,
              a4 = 0.f, a5 = 0.f, a6 = 0.f, a7 = 0.f;
        uint4v q[8];
        #pragma unroll
        for (int e = 0; e < 8; ++e) GLOAD4(q[e], o[e]);
        #pragma unroll
        for (int e = 0; e < 8; ++e) { VMWAIT(7); CONSUME(q[e]); GLOAD4(q[e], o[e + 8]); }
        VMWAIT(7); CONSUME(q[0]);
        VMWAIT(6); CONSUME(q[1]);
        VMWAIT(5); CONSUME(q[2]);
        VMWAIT(4); CONSUME(q[3]);
        VMWAIT(3); CONSUME(q[4]);
        VMWAIT(2); CONSUME(q[5]);
        VMWAIT(1); CONSUME(q[6]);
        VMWAIT(0); CONSUME(q[7]);
        us8 ov;
        ov[0] = f2bf(a0); ov[1] = f2bf(a1); ov[2] = f2bf(a2); ov[3] = f2bf(a3);
        ov[4] = f2bf(a4); ov[5] = f2bf(a5); ov[6] = f2bf(a6); ov[7] = f2bf(a7);
        *(us8*)&sIn[rA][l16 * 8] = ov;
    }

    // ================= row B gather (after region A drained) =================
    {
        unsigned o[16];
        #pragma unroll
        for (int e = 0; e < 16; ++e)
            o[e] = (unsigned)__shfl(suB, wbase + e) * 256u + (unsigned)l16 * 16u;
        float a0 = 0.f, a1 = 0.f, a2 = 0.f, a3 = 0.f,
              a4 = 0.f, a5 = 0.f, a6 = 0.f, a7 = 0.f;
        uint4v q[8];
        #pragma unroll
        for (int e = 0; e < 8; ++e) GLOAD4(q[e], o[e]);
        #pragma unroll
        for (int e = 0; e < 8; ++e) { VMWAIT(7); CONSUME(q[e]); GLOAD4(q[e], o[e + 8]); }
        VMWAIT(7); CONSUME(q[0]);
        VMWAIT(6); CONSUME(q[1]);
        VMWAIT(5); CONSUME(q[2]);
        VMWAIT(4); CONSUME(q[3]);
        VMWAIT(3); CONSUME(q[4]);
        VMWAIT(2); CONSUME(q[5]);
        VMWAIT(1); CONSUME(q[6]);
        VMWAIT(0); CONSUME(q[7]);
        us8 ov;
        ov[0] = f2bf(a0); ov[1] = f2bf(a1); ov[2] = f2bf(a2); ov[3] = f2bf(a3);
        ov[4] = f2bf(a4); ov[5] = f2bf(a5); ov[6] = f2bf(a6); ov[7] = f2bf(a7);
        *(us8*)&sIn[rB][l16 * 8] = ov;
    }
    __syncthreads();

    // ---- MFMA stage: wave w -> row-tile (w>>1), col-fragments (w&1)*4 .. +3 ----
    const int w = tid >> 6, wl = tid & 63;
    const int lc = wl & 15;
    const int kb = (wl >> 4) * 8;
    const int rt = w >> 1;
    const int cfb = (w & 1) * 4;
    f32x4 acc[4];
    #pragma unroll
    for (int cf = 0; cf < 4; ++cf) acc[cf] = (f32x4){0.f, 0.f, 0.f, 0.f};

    #pragma unroll
    for (int ks = 0; ks < 8; ++ks) {
        short8 af = *(const short8*)&sIn[rt * 16 + lc][ks * 32 + kb];
        #pragma unroll
        for (int cf = 0; cf < 4; ++cf) {
            short8 bfr = *(const short8*)(Bt + (size_t)((cfb + cf) * 16 + lc) * K2 + ks * 32 + kb);
            acc[cf] = __builtin_amdgcn_mfma_f32_16x16x32_bf16(af, bfr, acc[cf], 0, 0, 0);
        }
    }

    // ---- epilogue: out = relu(acc + b) - agg/16 ----
    const int rbase = (wl >> 4) * 4;   // C/D: col=lane&15, row=(lane>>4)*4+reg
    #pragma unroll
    for (int cf = 0; cf < 4; ++cf) {
        const int col = (cfb + cf) * 16 + lc;
        const float bv = bias[col];
        #pragma unroll
        for (int j = 0; j < 4; ++j) {
            const int trow = rt * 16 + rbase + j;
            const int grow = r0 + trow;
            float v = fmaxf(acc[cf][j] + bv, 0.f) - bf2f(sIn[trow][col]) * (1.0f / DEG);
            if (outb) outb[(size_t)grow * F + col] = f2bf(v);
            else      outf[(size_t)grow * F + col] = v;
        }
    }
}

extern "C" void kernel_launch(void* const* d_in, const int* in_sizes, int n_in,
                              void* d_out, int out_size, void* d_ws, size_t ws_size,
                              hipStream_t stream) {
    const float* x   = (const float*)d_in[0];
    const int*   ei  = (const int*)d_in[1];    // [2,E] row-major: src first
    const float* W0  = (const float*)d_in[2];
    const float* b0  = (const float*)d_in[3];
    const float* Wr0 = (const float*)d_in[4];
    const float* W1  = (const float*)d_in[5];
    const float* b1  = (const float*)d_in[6];
    const float* Wr1 = (const float*)d_in[7];
    const int* src = ei;                        // first E entries

    // workspace layout: xb 25.6MB | h1b 25.6MB | Bt 128KB
    unsigned short* xb  = (unsigned short*)d_ws;
    unsigned short* h1b = xb  + (size_t)N_NODES * F;
    unsigned short* Bt  = h1b + (size_t)N_NODES * F;

    cast_x_kernel<<<(N_NODES * F / 4 + 255) / 256, 256, 0, stream>>>(x, xb);
    build_bt_kernel<<<256, 256, 0, stream>>>(W0, Wr0, W1, Wr1, Bt);

    const int nb = N_NODES / TILE;   // 3125
    layer_kernel<<<nb, 256, 0, stream>>>(xb,  Bt,         b0, src, h1b,    nullptr);
    layer_kernel<<<nb, 256, 0, stream>>>(h1b, Bt + 32768, b1, src, nullptr, (float*)d_out);
}

// Round 9
// 173.439 us; speedup vs baseline: 1.6002x; 1.0730x over previous
//
#include <hip/hip_runtime.h>

// net_71322226917474: 2-layer GNN (SAGE-like) on MI355X.
// dst = repeat(arange(N),16) -> edges of node j are j*16..j*16+15, deg==16.
// bf16 matmul path (threshold 0.645), f32 accumulate.
// R9 = R2 gather structure with TILE=16: 6250 blocks -> 3.05 occupancy rounds
//      (fixes grid quantization; R2's 3125/8-resident = 1.53 rounds capped
//      occupancy at ~66%). Discriminator: occupancy-neutral => L3->L2 fill
//      rate (~2.15 TB/s compulsory 197MB/layer) is the roofline.

#define N_NODES 100000
#define DEG 16
#define F 128
#define K2 256      // combined K = [agg | h]
#define TILE 16     // rows per block; 100000 = 6250 * 16 exactly
#define LDP 264     // padded LDS row (shorts): 528B stride

typedef __attribute__((ext_vector_type(8))) short short8;
typedef __attribute__((ext_vector_type(4))) float f32x4;
typedef __attribute__((ext_vector_type(4))) unsigned short us4;
typedef __attribute__((ext_vector_type(8))) unsigned short us8;

__device__ __forceinline__ unsigned short f2bf(float f) {
    unsigned u = __builtin_bit_cast(unsigned, f);
    u += 0x7FFFu + ((u >> 16) & 1u);   // RNE
    return (unsigned short)(u >> 16);
}
__device__ __forceinline__ float bf2f(unsigned short h) {
    return __builtin_bit_cast(float, (unsigned)h << 16);
}

// ---- fused prep: blocks 0..255 build Bt; blocks 256.. cast x -> xb ----
__global__ void prep_kernel(const float* __restrict__ x, unsigned short* __restrict__ xb,
                            const float* __restrict__ W0, const float* __restrict__ Wr0,
                            const float* __restrict__ W1, const float* __restrict__ Wr1,
                            unsigned short* __restrict__ Bt) {
    if (blockIdx.x < 256) {
        int t = blockIdx.x * 256 + threadIdx.x;             // 0..65535
        int layer = t >> 15;
        int n = (t >> 8) & 127;
        int k = t & 255;
        const float* W  = layer ? W1  : W0;
        const float* Wr = layer ? Wr1 : Wr0;
        float v = (k < 128) ? W[n * 128 + k] : Wr[n * 128 + (k - 128)];
        Bt[t] = f2bf(v);
    } else {
        int i = (blockIdx.x - 256) * 256 + threadIdx.x;     // one thread per 4 elems
        const float4 v = ((const float4*)x)[i];
        us4 o; o.x = f2bf(v.x); o.y = f2bf(v.y); o.z = f2bf(v.z); o.w = f2bf(v.w);
        ((us4*)xb)[i] = o;
    }
}

// ---- one layer: gather agg, [agg|h] @ Bt^T via MFMA, relu, -agg/16 ----
__global__ __launch_bounds__(256, 8) void layer_kernel(
    const unsigned short* __restrict__ hb,   // [N][128] bf16 input
    const unsigned short* __restrict__ Bt,   // [128][256] bf16 combined weights
    const float* __restrict__ bias,          // [128] f32
    const int* __restrict__ src,             // [E] edge sources (dst implicit: e/16)
    unsigned short* __restrict__ outb,       // bf16 out (layer 0) or null
    float* __restrict__ outf)                // f32 out (layer 1) or null
{
    __shared__ unsigned short sIn[TILE][LDP];   // [row][0:128)=agg, [128:256)=h
    const int tid = threadIdx.x;
    const int r0 = blockIdx.x * TILE;

    // ---- gather: 16 groups of 16 lanes; group g owns row g ----
    const int g16 = tid >> 4, l16 = tid & 15;
    const int wbase = tid & 48;                 // group's lane base within wave
    const int grow = r0 + g16;

    const int su = src[grow * DEG + l16];       // 16 lanes hold the 16 src indices
    const us8 own = *(const us8*)(hb + (size_t)grow * F + l16 * 8);

    float a0 = 0.f, a1 = 0.f, a2 = 0.f, a3 = 0.f,
          a4 = 0.f, a5 = 0.f, a6 = 0.f, a7 = 0.f;
    #pragma unroll
    for (int e = 0; e < DEG; ++e) {
        const int idx = __shfl(su, wbase + e);  // broadcast within 16-lane group
        const us8 v = *(const us8*)(hb + (size_t)idx * F + l16 * 8);
        a0 += bf2f(v[0]); a1 += bf2f(v[1]); a2 += bf2f(v[2]); a3 += bf2f(v[3]);
        a4 += bf2f(v[4]); a5 += bf2f(v[5]); a6 += bf2f(v[6]); a7 += bf2f(v[7]);
    }
    {
        us8 o;
        o[0] = f2bf(a0); o[1] = f2bf(a1); o[2] = f2bf(a2); o[3] = f2bf(a3);
        o[4] = f2bf(a4); o[5] = f2bf(a5); o[6] = f2bf(a6); o[7] = f2bf(a7);
        *(us8*)&sIn[g16][l16 * 8] = o;
        *(us8*)&sIn[g16][128 + l16 * 8] = own;  // second K-half
    }
    __syncthreads();

    // ---- MFMA: single 16-row tile; wave w owns col fragments w*2, w*2+1 ----
    const int w = tid >> 6, wl = tid & 63;
    const int lc = wl & 15;
    const int kb = (wl >> 4) * 8;
    f32x4 acc[2];
    acc[0] = (f32x4){0.f, 0.f, 0.f, 0.f};
    acc[1] = (f32x4){0.f, 0.f, 0.f, 0.f};

    #pragma unroll
    for (int ks = 0; ks < 8; ++ks) {
        short8 af = *(const short8*)&sIn[lc][ks * 32 + kb];
        #pragma unroll
        for (int cf = 0; cf < 2; ++cf) {
            short8 bfr = *(const short8*)(Bt + (size_t)((w * 2 + cf) * 16 + lc) * K2 + ks * 32 + kb);
            acc[cf] = __builtin_amdgcn_mfma_f32_16x16x32_bf16(af, bfr, acc[cf], 0, 0, 0);
        }
    }

    // ---- epilogue: out = relu(acc + b) - agg/16 ----
    const int rbase = (wl >> 4) * 4;   // C/D: col=lane&15, row=(lane>>4)*4+reg
    #pragma unroll
    for (int cf = 0; cf < 2; ++cf) {
        const int col = (w * 2 + cf) * 16 + lc;
        const float bv = bias[col];
        #pragma unroll
        for (int j = 0; j < 4; ++j) {
            const int trow = rbase + j;
            const int gr = r0 + trow;
            float v = fmaxf(acc[cf][j] + bv, 0.f) - bf2f(sIn[trow][col]) * (1.0f / DEG);
            if (outb) outb[(size_t)gr * F + col] = f2bf(v);
            else      outf[(size_t)gr * F + col] = v;
        }
    }
}

extern "C" void kernel_launch(void* const* d_in, const int* in_sizes, int n_in,
                              void* d_out, int out_size, void* d_ws, size_t ws_size,
                              hipStream_t stream) {
    const float* x   = (const float*)d_in[0];
    const int*   ei  = (const int*)d_in[1];    // [2,E] row-major: src first
    const float* W0  = (const float*)d_in[2];
    const float* b0  = (const float*)d_in[3];
    const float* Wr0 = (const float*)d_in[4];
    const float* W1  = (const float*)d_in[5];
    const float* b1  = (const float*)d_in[6];
    const float* Wr1 = (const float*)d_in[7];
    const int* src = ei;                        // first E entries

    // workspace layout: xb 25.6MB | h1b 25.6MB | Bt 128KB
    unsigned short* xb  = (unsigned short*)d_ws;
    unsigned short* h1b = xb  + (size_t)N_NODES * F;
    unsigned short* Bt  = h1b + (size_t)N_NODES * F;

    // fused prep: 256 Bt-blocks + 12500 cast-blocks
    prep_kernel<<<256 + (N_NODES * F / 4) / 256, 256, 0, stream>>>(x, xb, W0, Wr0, W1, Wr1, Bt);

    const int nb = N_NODES / TILE;   // 6250 exactly
    layer_kernel<<<nb, 256, 0, stream>>>(xb,  Bt,         b0, src, h1b,    nullptr);
    layer_kernel<<<nb, 256, 0, stream>>>(h1b, Bt + 32768, b1, src, nullptr, (float*)d_out);
}